// Round 1
// baseline (2762.573 us; speedup 1.0000x reference)
//
#include <hip/hip_runtime.h>
#include <math.h>

// Problem constants
#define BATCH 2048
#define DM    1024   // D
#define HF    4096   // H
#define NE    8      // experts
// TOP_K = 2

// d_out layout (floats, concatenated reference outputs)
#define OFF_GATES (BATCH*DM)            // 2097152
#define OFF_TOPI  (OFF_GATES + BATCH*NE)
#define OFF_LOSS  (OFF_TOPI + BATCH*2)
#define OFF_UTIL  (OFF_LOSS + 1)

// d_ws layout (bytes)
//   0   : cnt[8]   int      (rows assigned per expert)
//   32  : imp[8]   float    (sum of gate values per expert)
//   64  : loadv[8] float    (sum of full-softmax per expert)
//   96  : offs[9]  int      (prefix sum of cnt)
//   256 : rows[NE*BATCH]  int
//   +64K: rgate[NE*BATCH] float
//   +64K: hbuf[(2*BATCH+256) x 1024] float   (one H-slab of gelu activations)
#define WS_ROWS_OFF  256
#define WS_RGATE_OFF (WS_ROWS_OFF + NE*BATCH*4)
#define WS_HBUF_OFF  (WS_RGATE_OFF + NE*BATCH*4)
#define HROWS        (2*BATCH + 256)          // 4096 instances + padding
#define WS_NEEDED    ((size_t)WS_HBUF_OFF + (size_t)HROWS*1024*4)

// GEMM tiling
#define BM  64
#define BN  128
#define BKK 16
#define RT  (BATCH/BM)   // 32 row tiles (worst case one expert owns all rows)
#define CT1 (1024/BN)    // 8 col tiles per 1024-wide slab
#define NSLAB 4          // H split into 4 slabs of 1024

__device__ __forceinline__ float gelu_f(float v) {
    // exact gelu: x * 0.5 * (1 + erf(x/sqrt(2)))
    return 0.5f * v * (1.f + erff(v * 0.70710678118654752440f));
}

__device__ __forceinline__ void fma4(float4& a, float s, const float4& b) {
    a.x = fmaf(s, b.x, a.x);
    a.y = fmaf(s, b.y, a.y);
    a.z = fmaf(s, b.z, a.z);
    a.w = fmaf(s, b.w, a.w);
}

// ---------------- gate: logits, top-2 softmax, bookkeeping ----------------
__global__ __launch_bounds__(256) void gate_kernel(
    const float* __restrict__ x, const float* __restrict__ Wg,
    const float* __restrict__ bg, float* __restrict__ out,
    int* __restrict__ cnt, float* __restrict__ imp, float* __restrict__ loadv,
    int* __restrict__ rowsl, float* __restrict__ rgate)
{
    int lane = threadIdx.x & 63;
    int row  = blockIdx.x * 4 + (threadIdx.x >> 6);   // one wave per row

    float a[NE] = {0.f,0.f,0.f,0.f,0.f,0.f,0.f,0.f};
    const float* xr = x + (size_t)row * DM;
    #pragma unroll
    for (int j = 0; j < DM/64; ++j) {
        int d = j*64 + lane;
        float xv = xr[d];
        const float4* wp = reinterpret_cast<const float4*>(Wg + (size_t)d*NE);
        float4 w0 = wp[0], w1v = wp[1];
        a[0] += xv*w0.x;  a[1] += xv*w0.y;  a[2] += xv*w0.z;  a[3] += xv*w0.w;
        a[4] += xv*w1v.x; a[5] += xv*w1v.y; a[6] += xv*w1v.z; a[7] += xv*w1v.w;
    }
    #pragma unroll
    for (int e = 0; e < NE; ++e) {
        #pragma unroll
        for (int off = 32; off > 0; off >>= 1) a[e] += __shfl_xor(a[e], off);
    }
    if (lane == 0) {
        float lg[NE];
        #pragma unroll
        for (int e = 0; e < NE; ++e) lg[e] = a[e] + bg[e];
        // full softmax -> load
        float m = lg[0];
        #pragma unroll
        for (int e = 1; e < NE; ++e) m = fmaxf(m, lg[e]);
        float ex[NE], s = 0.f;
        #pragma unroll
        for (int e = 0; e < NE; ++e) { ex[e] = expf(lg[e] - m); s += ex[e]; }
        #pragma unroll
        for (int e = 0; e < NE; ++e) atomicAdd(&loadv[e], ex[e] / s);
        // top-2 (ties -> lowest index, matching lax.top_k)
        int i1 = 0;
        #pragma unroll
        for (int e = 1; e < NE; ++e) if (lg[e] > lg[i1]) i1 = e;
        int i2 = (i1 == 0) ? 1 : 0;
        #pragma unroll
        for (int e = 0; e < NE; ++e) if (e != i1 && lg[e] > lg[i2]) i2 = e;
        float e2 = expf(lg[i2] - lg[i1]);       // v2 <= v1, stable
        float g1 = 1.f / (1.f + e2);
        float g2 = e2  / (1.f + e2);
        float* gout = out + OFF_GATES + (size_t)row*NE;
        #pragma unroll
        for (int e = 0; e < NE; ++e) gout[e] = (e==i1) ? g1 : ((e==i2) ? g2 : 0.f);
        out[OFF_TOPI + row*2 + 0] = (float)i1;  // indices as floats (harness concats fp32)
        out[OFF_TOPI + row*2 + 1] = (float)i2;
        atomicAdd(&imp[i1], g1);
        atomicAdd(&imp[i2], g2);
        int p1 = atomicAdd(&cnt[i1], 1);
        rowsl[i1*BATCH + p1] = row;  rgate[i1*BATCH + p1] = g1;
        int p2 = atomicAdd(&cnt[i2], 1);
        rowsl[i2*BATCH + p2] = row;  rgate[i2*BATCH + p2] = g2;
    }
}

// ---------------- finalize: loss, utilization, prefix offsets ----------------
__global__ void finalize_kernel(const int* __restrict__ cnt, const float* __restrict__ imp,
                                const float* __restrict__ loadv, int* __restrict__ offs,
                                float* __restrict__ out)
{
    if (threadIdx.x == 0) {
        float mi = 0.f, ml = 0.f;
        for (int e = 0; e < NE; ++e) { mi += imp[e]; ml += loadv[e]; }
        mi *= (1.f/NE); ml *= (1.f/NE);
        float vi = 0.f, vl = 0.f;
        for (int e = 0; e < NE; ++e) {
            float di = imp[e]  - mi; vi += di*di;
            float dl = loadv[e]- ml; vl += dl*dl;
        }
        vi *= (1.f/(NE-1)); vl *= (1.f/(NE-1));   // ddof=1
        out[OFF_LOSS] = sqrtf(vi)/(mi + 1e-6f) + sqrtf(vl)/(ml + 1e-6f);
        int o = 0;
        for (int e = 0; e < NE; ++e) { offs[e] = o; o += cnt[e]; }
        offs[NE] = o;
    }
    if (threadIdx.x < NE)
        out[OFF_UTIL + threadIdx.x] = (float)cnt[threadIdx.x] * (1.f/BATCH);
}

// ---------------- GEMM1: h = gelu(x_gathered @ w1_slab + b1) ----------------
__global__ __launch_bounds__(256, 4) void gemm1_kernel(
    const float* __restrict__ x, const float* __restrict__ w1, const float* __restrict__ b1,
    const int* __restrict__ cnt, const int* __restrict__ offs,
    const int* __restrict__ rowsl, float* __restrict__ hbuf, int slab)
{
    int bid = blockIdx.x;
    int ct = bid & (CT1-1);
    int rt = (bid >> 3) & (RT-1);
    int e  = bid >> 8;
    int ne = cnt[e];
    int r0 = rt * BM;
    if (r0 >= ne) return;
    int base = offs[e];

    __shared__ float As[BKK][BM+4];
    __shared__ float Bs[BKK][BN];
    __shared__ int   rid[BM];

    int t = threadIdx.x;
    if (t < BM) {
        int i = r0 + t;
        rid[t] = rowsl[e*BATCH + (i < ne ? i : (ne-1))];
    }
    __syncthreads();

    int tx = t & 31;          // 32 col groups of 4
    int ty = t >> 5;          // 8 row groups of 8
    float4 acc[8];
    #pragma unroll
    for (int i = 0; i < 8; ++i) acc[i] = make_float4(0.f,0.f,0.f,0.f);

    const float* w1e = w1 + (size_t)e*DM*HF + (size_t)slab*1024 + ct*BN;
    int am_ = t >> 2;         // 0..63  (A row)
    int ak_ = (t & 3) * 4;    // 0,4,8,12 (A k quad)
    int bk_ = t >> 5;         // 0..7   (B k, +8 for second)
    int bn_ = (t & 31) * 4;   // B col quad

    for (int k0 = 0; k0 < DM; k0 += BKK) {
        float4 av  = *reinterpret_cast<const float4*>(&x[(size_t)rid[am_]*DM + k0 + ak_]);
        float4 bv0 = *reinterpret_cast<const float4*>(&w1e[(size_t)(k0 + bk_    )*HF + bn_]);
        float4 bv1 = *reinterpret_cast<const float4*>(&w1e[(size_t)(k0 + bk_ + 8)*HF + bn_]);
        __syncthreads();   // previous iteration done reading LDS
        As[ak_+0][am_] = av.x; As[ak_+1][am_] = av.y;
        As[ak_+2][am_] = av.z; As[ak_+3][am_] = av.w;
        *reinterpret_cast<float4*>(&Bs[bk_  ][bn_]) = bv0;
        *reinterpret_cast<float4*>(&Bs[bk_+8][bn_]) = bv1;
        __syncthreads();
        #pragma unroll
        for (int k = 0; k < BKK; ++k) {
            float4 b0 = *reinterpret_cast<const float4*>(&Bs[k][tx*4]);
            float4 a0 = *reinterpret_cast<const float4*>(&As[k][ty*8]);
            float4 a1 = *reinterpret_cast<const float4*>(&As[k][ty*8+4]);
            float am[8] = {a0.x,a0.y,a0.z,a0.w,a1.x,a1.y,a1.z,a1.w};
            #pragma unroll
            for (int i = 0; i < 8; ++i) fma4(acc[i], am[i], b0);
        }
    }

    const float* b1e = b1 + e*HF + slab*1024 + ct*BN;
    float4 bb = *reinterpret_cast<const float4*>(&b1e[tx*4]);
    #pragma unroll
    for (int i = 0; i < 8; ++i) {
        int gi = r0 + ty*8 + i;
        if (gi < ne) {
            float4 v = acc[i];
            float4 o;
            o.x = gelu_f(v.x + bb.x); o.y = gelu_f(v.y + bb.y);
            o.z = gelu_f(v.z + bb.z); o.w = gelu_f(v.w + bb.w);
            *reinterpret_cast<float4*>(&hbuf[(size_t)(base + gi)*1024 + ct*BN + tx*4]) = o;
        }
    }
}

// ---------------- GEMM2: out += gate * (h @ w2_slab + b2) ----------------
__global__ __launch_bounds__(256, 4) void gemm2_kernel(
    const float* __restrict__ hbuf, const float* __restrict__ w2, const float* __restrict__ b2,
    const int* __restrict__ cnt, const int* __restrict__ offs,
    const int* __restrict__ rowsl, const float* __restrict__ rgate,
    float* __restrict__ out, int slab)
{
    int bid = blockIdx.x;
    int ct = bid & (CT1-1);
    int rt = (bid >> 3) & (RT-1);
    int e  = bid >> 8;
    int ne = cnt[e];
    int r0 = rt * BM;
    if (r0 >= ne) return;
    int base = offs[e];

    __shared__ float As[BKK][BM+4];
    __shared__ float Bs[BKK][BN];

    int t = threadIdx.x;
    int tx = t & 31;
    int ty = t >> 5;
    float4 acc[8];
    #pragma unroll
    for (int i = 0; i < 8; ++i) acc[i] = make_float4(0.f,0.f,0.f,0.f);

    const float* w2e = w2 + (size_t)e*HF*DM + (size_t)slab*1024*DM + ct*BN;
    int am_ = t >> 2;
    int ak_ = (t & 3) * 4;
    int bk_ = t >> 5;
    int bn_ = (t & 31) * 4;

    for (int k0 = 0; k0 < 1024; k0 += BKK) {
        // rows past ne read padded garbage; their results are discarded below
        float4 av  = *reinterpret_cast<const float4*>(&hbuf[(size_t)(base + r0 + am_)*1024 + k0 + ak_]);
        float4 bv0 = *reinterpret_cast<const float4*>(&w2e[(size_t)(k0 + bk_    )*DM + bn_]);
        float4 bv1 = *reinterpret_cast<const float4*>(&w2e[(size_t)(k0 + bk_ + 8)*DM + bn_]);
        __syncthreads();
        As[ak_+0][am_] = av.x; As[ak_+1][am_] = av.y;
        As[ak_+2][am_] = av.z; As[ak_+3][am_] = av.w;
        *reinterpret_cast<float4*>(&Bs[bk_  ][bn_]) = bv0;
        *reinterpret_cast<float4*>(&Bs[bk_+8][bn_]) = bv1;
        __syncthreads();
        #pragma unroll
        for (int k = 0; k < BKK; ++k) {
            float4 b0 = *reinterpret_cast<const float4*>(&Bs[k][tx*4]);
            float4 a0 = *reinterpret_cast<const float4*>(&As[k][ty*8]);
            float4 a1 = *reinterpret_cast<const float4*>(&As[k][ty*8+4]);
            float am[8] = {a0.x,a0.y,a0.z,a0.w,a1.x,a1.y,a1.z,a1.w};
            #pragma unroll
            for (int i = 0; i < 8; ++i) fma4(acc[i], am[i], b0);
        }
    }

    float4 bb = make_float4(0.f,0.f,0.f,0.f);
    if (slab == 0)  // add b2 exactly once per (row, expert)
        bb = *reinterpret_cast<const float4*>(&b2[(size_t)e*DM + ct*BN + tx*4]);
    #pragma unroll
    for (int i = 0; i < 8; ++i) {
        int gi = r0 + ty*8 + i;
        if (gi < ne) {
            int   brow = rowsl[e*BATCH + gi];
            float g    = rgate[e*BATCH + gi];
            float* op  = out + (size_t)brow*DM + ct*BN + tx*4;
            float4 v = acc[i];
            atomicAdd(&op[0], g*(v.x + bb.x));
            atomicAdd(&op[1], g*(v.y + bb.y));
            atomicAdd(&op[2], g*(v.z + bb.z));
            atomicAdd(&op[3], g*(v.w + bb.w));
        }
    }
}

extern "C" void kernel_launch(void* const* d_in, const int* in_sizes, int n_in,
                              void* d_out, int out_size, void* d_ws, size_t ws_size,
                              hipStream_t stream) {
    const float* x  = (const float*)d_in[0];
    const float* Wg = (const float*)d_in[1];
    const float* bg = (const float*)d_in[2];
    const float* w1 = (const float*)d_in[3];
    const float* b1 = (const float*)d_in[4];
    const float* w2 = (const float*)d_in[5];
    const float* b2 = (const float*)d_in[6];
    float* out = (float*)d_out;

    if (ws_size < WS_NEEDED) return;  // would corrupt memory otherwise

    char* ws = (char*)d_ws;
    int*   cnt   = (int*)  (ws + 0);
    float* imp   = (float*)(ws + 32);
    float* loadv = (float*)(ws + 64);
    int*   offs  = (int*)  (ws + 96);
    int*   rowsl = (int*)  (ws + WS_ROWS_OFF);
    float* rgate = (float*)(ws + WS_RGATE_OFF);
    float* hbuf  = (float*)(ws + WS_HBUF_OFF);

    hipMemsetAsync(d_out, 0, (size_t)out_size * sizeof(float), stream);
    hipMemsetAsync(d_ws, 0, 256, stream);

    gate_kernel<<<BATCH/4, 256, 0, stream>>>(x, Wg, bg, out, cnt, imp, loadv, rowsl, rgate);
    finalize_kernel<<<1, 64, 0, stream>>>(cnt, imp, loadv, offs, out);

    for (int s = 0; s < NSLAB; ++s) {
        gemm1_kernel<<<NE*RT*CT1, 256, 0, stream>>>(x, w1, b1, cnt, offs, rowsl, hbuf, s);
        gemm2_kernel<<<NE*RT*CT1, 256, 0, stream>>>(hbuf, w2, b2, cnt, offs, rowsl, rgate, out, s);
    }
}

// Round 3
// 1219.378 us; speedup vs baseline: 2.2656x; 2.2656x over previous
//
#include <hip/hip_runtime.h>
#include <hip/hip_bf16.h>
#include <math.h>

#define BATCH 2048
#define DM    1024
#define HF    4096
#define NE    8

// d_out layout (floats)
#define OFF_GATES (BATCH*DM)
#define OFF_TOPI  (OFF_GATES + BATCH*NE)
#define OFF_LOSS  (OFF_TOPI + BATCH*2)
#define OFF_UTIL  (OFF_LOSS + 1)

// d_ws layout (bytes)
#define WS_ROWS   256
#define WS_RGATE  (WS_ROWS + NE*BATCH*4)
#define WS_XB     (WS_RGATE + NE*BATCH*4)          // bf16 copy of x [2048][1024]
#define WS_HBUF   (WS_XB + BATCH*DM*2)             // bf16 h slab [4224][slabh]
#define HPAD      4224

typedef __attribute__((ext_vector_type(8))) short bf16x8;
typedef __attribute__((ext_vector_type(4))) float f32x4;

__device__ __forceinline__ unsigned short f2bf(float f) {
    __hip_bfloat16 h = __float2bfloat16(f);
    return *reinterpret_cast<unsigned short*>(&h);
}
__device__ __forceinline__ float f4get(const float4& v, int j) {
    return j == 0 ? v.x : j == 1 ? v.y : j == 2 ? v.z : v.w;
}
__device__ __forceinline__ float gelu_f(float v) {
    return 0.5f * v * (1.f + erff(v * 0.70710678118654752440f));
}

// ---------------- x -> bf16 copy ----------------
__global__ __launch_bounds__(256) void cvt_x(const float* __restrict__ x, unsigned short* __restrict__ xb) {
    int i = blockIdx.x * 256 + threadIdx.x;          // one float4 per thread
    float4 v = reinterpret_cast<const float4*>(x)[i];
    uint2 o;
    o.x = (unsigned)f2bf(v.x) | ((unsigned)f2bf(v.y) << 16);
    o.y = (unsigned)f2bf(v.z) | ((unsigned)f2bf(v.w) << 16);
    reinterpret_cast<uint2*>(xb)[i] = o;
}

// ---------------- gate ----------------
__global__ __launch_bounds__(256) void gate_kernel(
    const float* __restrict__ x, const float* __restrict__ Wg,
    const float* __restrict__ bg, float* __restrict__ out,
    int* __restrict__ cnt, float* __restrict__ imp, float* __restrict__ loadv,
    int* __restrict__ rowsl, float* __restrict__ rgate)
{
    int lane = threadIdx.x & 63;
    int row  = blockIdx.x * 4 + (threadIdx.x >> 6);

    float a[NE] = {0.f,0.f,0.f,0.f,0.f,0.f,0.f,0.f};
    const float* xr = x + (size_t)row * DM;
    #pragma unroll
    for (int j = 0; j < DM/64; ++j) {
        int d = j*64 + lane;
        float xv = xr[d];
        const float4* wp = reinterpret_cast<const float4*>(Wg + (size_t)d*NE);
        float4 w0 = wp[0], w1v = wp[1];
        a[0] += xv*w0.x;  a[1] += xv*w0.y;  a[2] += xv*w0.z;  a[3] += xv*w0.w;
        a[4] += xv*w1v.x; a[5] += xv*w1v.y; a[6] += xv*w1v.z; a[7] += xv*w1v.w;
    }
    #pragma unroll
    for (int e = 0; e < NE; ++e) {
        #pragma unroll
        for (int off = 32; off > 0; off >>= 1) a[e] += __shfl_xor(a[e], off);
    }
    if (lane == 0) {
        float lg[NE];
        #pragma unroll
        for (int e = 0; e < NE; ++e) lg[e] = a[e] + bg[e];
        float m = lg[0];
        #pragma unroll
        for (int e = 1; e < NE; ++e) m = fmaxf(m, lg[e]);
        float ex[NE], s = 0.f;
        #pragma unroll
        for (int e = 0; e < NE; ++e) { ex[e] = expf(lg[e] - m); s += ex[e]; }
        #pragma unroll
        for (int e = 0; e < NE; ++e) atomicAdd(&loadv[e], ex[e] / s);
        int i1 = 0;
        #pragma unroll
        for (int e = 1; e < NE; ++e) if (lg[e] > lg[i1]) i1 = e;
        int i2 = (i1 == 0) ? 1 : 0;
        #pragma unroll
        for (int e = 0; e < NE; ++e) if (e != i1 && lg[e] > lg[i2]) i2 = e;
        float e2 = expf(lg[i2] - lg[i1]);
        float g1 = 1.f / (1.f + e2);
        float g2 = e2  / (1.f + e2);
        float* gout = out + OFF_GATES + (size_t)row*NE;
        #pragma unroll
        for (int e = 0; e < NE; ++e) gout[e] = (e==i1) ? g1 : ((e==i2) ? g2 : 0.f);
        out[OFF_TOPI + row*2 + 0] = (float)i1;
        out[OFF_TOPI + row*2 + 1] = (float)i2;
        atomicAdd(&imp[i1], g1);
        atomicAdd(&imp[i2], g2);
        int p1 = atomicAdd(&cnt[i1], 1);
        rowsl[i1*BATCH + p1] = row;  rgate[i1*BATCH + p1] = g1;
        int p2 = atomicAdd(&cnt[i2], 1);
        rowsl[i2*BATCH + p2] = row;  rgate[i2*BATCH + p2] = g2;
    }
}

// ---------------- finalize ----------------
__global__ void finalize_kernel(const int* __restrict__ cnt, const float* __restrict__ imp,
                                const float* __restrict__ loadv, int* __restrict__ offs,
                                float* __restrict__ out)
{
    if (threadIdx.x == 0) {
        float mi = 0.f, ml = 0.f;
        for (int e = 0; e < NE; ++e) { mi += imp[e]; ml += loadv[e]; }
        mi *= (1.f/NE); ml *= (1.f/NE);
        float vi = 0.f, vl = 0.f;
        for (int e = 0; e < NE; ++e) {
            float di = imp[e]  - mi; vi += di*di;
            float dl = loadv[e]- ml; vl += dl*dl;
        }
        vi *= (1.f/(NE-1)); vl *= (1.f/(NE-1));
        out[OFF_LOSS] = sqrtf(vi)/(mi + 1e-6f) + sqrtf(vl)/(ml + 1e-6f);
        int o = 0;
        for (int e = 0; e < NE; ++e) { offs[e] = o; o += cnt[e]; }
        offs[NE] = o;
    }
    if (threadIdx.x < NE)
        out[OFF_UTIL + threadIdx.x] = (float)cnt[threadIdx.x] * (1.f/BATCH);
}

// ===================== MFMA GEMM1: h = gelu(x_bf16 @ w1 + b1) =====================
// BM=BN=128, BK=32, 256 thr (4 waves 2x2), 4x4 frags/wave of 16x16x32.
__global__ __launch_bounds__(256) void gemm1_mfma(
    const unsigned short* __restrict__ xb, const float* __restrict__ w1,
    const float* __restrict__ b1, const int* __restrict__ cnt,
    const int* __restrict__ offs, const int* __restrict__ rowsl,
    unsigned short* __restrict__ hbuf, int slab, int slabh)
{
    int ctn = slabh >> 7;
    int bid = blockIdx.x;
    int rt = bid & 15;               // innermost: blocks sharing B-panel adjacent
    int ct = (bid >> 4) % ctn;
    int e  = bid / (16*ctn);
    int ne = cnt[e];
    int r0 = rt * 128;
    if (r0 >= ne) return;
    int base = offs[e];

    __shared__ __align__(16) unsigned short As[128*32];
    __shared__ __align__(16) unsigned short Bs[128*32];
    __shared__ int rid[128];

    int t = threadIdx.x;
    if (t < 128) { int gi = r0 + t; rid[t] = rowsl[e*BATCH + (gi < ne ? gi : ne-1)]; }
    __syncthreads();

    // ---- A staging constants (bf16 source, 16B/thread x2) ----
    int ar0 = t >> 2,        as0 = t & 3;
    int ar1 = 64 + (t >> 2), as1 = as0;
    const unsigned short* ag0 = xb + (size_t)rid[ar0]*DM + as0*8;
    const unsigned short* ag1 = xb + (size_t)rid[ar1]*DM + as1*8;
    int aw0 = ar0*32 + ((as0 ^ ((ar0 >> 2) & 3)) << 3);
    int aw1 = ar1*32 + ((as1 ^ ((ar1 >> 2) & 3)) << 3);

    // ---- B staging constants (fp32 [k][n] -> bf16 LDS [n][k]) ----
    int nq = t & 31, kq = t >> 5;
    const float* bgB = w1 + (size_t)e*DM*HF + (size_t)(4*kq)*HF + slab*slabh + ct*128 + 4*nq;
    int bw[4];
    #pragma unroll
    for (int jj = 0; jj < 4; ++jj) {
        int n = 4*nq + jj;
        bw[jj] = n*32 + (((kq >> 1) ^ ((n >> 2) & 3)) << 3) + ((kq & 1) << 2);
    }

    // ---- fragment read pointers (constant per lane) ----
    int lane = t & 63, wid = t >> 6, wr = wid >> 1, wc = wid & 1;
    int lr = lane & 15, lg = lane >> 4;
    const bf16x8* ap[4]; const bf16x8* bp[4];
    #pragma unroll
    for (int i = 0; i < 4; ++i) {
        int row = wr*64 + i*16 + lr;
        ap[i] = (const bf16x8*)&As[row*32 + ((lg ^ ((row >> 2) & 3)) << 3)];
    }
    #pragma unroll
    for (int j = 0; j < 4; ++j) {
        int n = wc*64 + j*16 + lr;
        bp[j] = (const bf16x8*)&Bs[n*32 + ((lg ^ ((n >> 2) & 3)) << 3)];
    }

    f32x4 acc[4][4];
    #pragma unroll
    for (int i = 0; i < 4; ++i)
        #pragma unroll
        for (int j = 0; j < 4; ++j) acc[i][j] = (f32x4){0.f,0.f,0.f,0.f};

    uint4 pa0, pa1; float4 pr0, pr1, pr2, pr3;
    pa0 = *(const uint4*)(ag0);
    pa1 = *(const uint4*)(ag1);
    { const float* p = bgB;
      pr0 = *(const float4*)(p); pr1 = *(const float4*)(p + HF);
      pr2 = *(const float4*)(p + 2*HF); pr3 = *(const float4*)(p + 3*HF); }

    for (int ks = 0; ks < DM/32; ++ks) {
        __syncthreads();
        *(uint4*)&As[aw0] = pa0;
        *(uint4*)&As[aw1] = pa1;
        #pragma unroll
        for (int jj = 0; jj < 4; ++jj) {
            uint2 o;
            o.x = (unsigned)f2bf(f4get(pr0,jj)) | ((unsigned)f2bf(f4get(pr1,jj)) << 16);
            o.y = (unsigned)f2bf(f4get(pr2,jj)) | ((unsigned)f2bf(f4get(pr3,jj)) << 16);
            *(uint2*)&Bs[bw[jj]] = o;
        }
        __syncthreads();
        if (ks + 1 < DM/32) {
            int k1 = (ks + 1) * 32;
            pa0 = *(const uint4*)(ag0 + k1);
            pa1 = *(const uint4*)(ag1 + k1);
            const float* p = bgB + (size_t)k1 * HF;
            pr0 = *(const float4*)(p); pr1 = *(const float4*)(p + HF);
            pr2 = *(const float4*)(p + 2*HF); pr3 = *(const float4*)(p + 3*HF);
        }
        bf16x8 af[4], bfr[4];
        #pragma unroll
        for (int i = 0; i < 4; ++i) af[i]  = *ap[i];
        #pragma unroll
        for (int j = 0; j < 4; ++j) bfr[j] = *bp[j];
        #pragma unroll
        for (int i = 0; i < 4; ++i)
            #pragma unroll
            for (int j = 0; j < 4; ++j)
                acc[i][j] = __builtin_amdgcn_mfma_f32_16x16x32_bf16(af[i], bfr[j], acc[i][j], 0, 0, 0);
    }

    const float* b1e = b1 + e*HF + slab*slabh + ct*128;
    #pragma unroll
    for (int j = 0; j < 4; ++j) {
        int ncol = wc*64 + j*16 + lr;
        float bb = b1e[ncol];
        #pragma unroll
        for (int i = 0; i < 4; ++i) {
            #pragma unroll
            for (int r = 0; r < 4; ++r) {
                int trow = wr*64 + i*16 + lg*4 + r;
                if (r0 + trow < ne) {
                    float v = gelu_f(acc[i][j][r] + bb);
                    hbuf[(size_t)(base + r0 + trow)*slabh + ct*128 + ncol] = f2bf(v);
                }
            }
        }
    }
}

// ===================== MFMA GEMM2: out += gate * (h @ w2 + b2) =====================
__global__ __launch_bounds__(256) void gemm2_mfma(
    const unsigned short* __restrict__ hbuf, const float* __restrict__ w2,
    const float* __restrict__ b2, const int* __restrict__ cnt,
    const int* __restrict__ offs, const int* __restrict__ rowsl,
    const float* __restrict__ rgate, float* __restrict__ out, int slab, int slabh)
{
    int bid = blockIdx.x;
    int rt = bid & 15;
    int ct = (bid >> 4) & 7;
    int e  = bid >> 7;
    int ne = cnt[e];
    int r0 = rt * 128;
    if (r0 >= ne) return;
    int base = offs[e];

    __shared__ __align__(16) unsigned short As[128*32];
    __shared__ __align__(16) unsigned short Bs[128*32];
    __shared__ int   rid[128];
    __shared__ float rg[128];

    int t = threadIdx.x;
    if (t < 128) {
        int gi = r0 + t; int ci = (gi < ne ? gi : ne-1);
        rid[t] = rowsl[e*BATCH + ci];
        rg[t]  = rgate[e*BATCH + ci];
    }
    __syncthreads();

    int ar0 = t >> 2,        as0 = t & 3;
    int ar1 = 64 + (t >> 2), as1 = as0;
    const unsigned short* ag0 = hbuf + (size_t)(base + r0 + ar0)*slabh + as0*8;
    const unsigned short* ag1 = hbuf + (size_t)(base + r0 + ar1)*slabh + as1*8;
    int aw0 = ar0*32 + ((as0 ^ ((ar0 >> 2) & 3)) << 3);
    int aw1 = ar1*32 + ((as1 ^ ((ar1 >> 2) & 3)) << 3);

    int nq = t & 31, kq = t >> 5;
    const float* bgB = w2 + (size_t)e*HF*DM + (size_t)(slab*slabh + 4*kq)*DM + ct*128 + 4*nq;
    int bw[4];
    #pragma unroll
    for (int jj = 0; jj < 4; ++jj) {
        int n = 4*nq + jj;
        bw[jj] = n*32 + (((kq >> 1) ^ ((n >> 2) & 3)) << 3) + ((kq & 1) << 2);
    }

    int lane = t & 63, wid = t >> 6, wr = wid >> 1, wc = wid & 1;
    int lr = lane & 15, lg = lane >> 4;
    const bf16x8* ap[4]; const bf16x8* bp[4];
    #pragma unroll
    for (int i = 0; i < 4; ++i) {
        int row = wr*64 + i*16 + lr;
        ap[i] = (const bf16x8*)&As[row*32 + ((lg ^ ((row >> 2) & 3)) << 3)];
    }
    #pragma unroll
    for (int j = 0; j < 4; ++j) {
        int n = wc*64 + j*16 + lr;
        bp[j] = (const bf16x8*)&Bs[n*32 + ((lg ^ ((n >> 2) & 3)) << 3)];
    }

    f32x4 acc[4][4];
    #pragma unroll
    for (int i = 0; i < 4; ++i)
        #pragma unroll
        for (int j = 0; j < 4; ++j) acc[i][j] = (f32x4){0.f,0.f,0.f,0.f};

    int steps = slabh >> 5;
    uint4 pa0, pa1; float4 pr0, pr1, pr2, pr3;
    pa0 = *(const uint4*)(ag0);
    pa1 = *(const uint4*)(ag1);
    { const float* p = bgB;
      pr0 = *(const float4*)(p); pr1 = *(const float4*)(p + DM);
      pr2 = *(const float4*)(p + 2*DM); pr3 = *(const float4*)(p + 3*DM); }

    for (int ks = 0; ks < steps; ++ks) {
        __syncthreads();
        *(uint4*)&As[aw0] = pa0;
        *(uint4*)&As[aw1] = pa1;
        #pragma unroll
        for (int jj = 0; jj < 4; ++jj) {
            uint2 o;
            o.x = (unsigned)f2bf(f4get(pr0,jj)) | ((unsigned)f2bf(f4get(pr1,jj)) << 16);
            o.y = (unsigned)f2bf(f4get(pr2,jj)) | ((unsigned)f2bf(f4get(pr3,jj)) << 16);
            *(uint2*)&Bs[bw[jj]] = o;
        }
        __syncthreads();
        if (ks + 1 < steps) {
            int k1 = (ks + 1) * 32;
            pa0 = *(const uint4*)(ag0 + k1);
            pa1 = *(const uint4*)(ag1 + k1);
            const float* p = bgB + (size_t)k1 * DM;
            pr0 = *(const float4*)(p); pr1 = *(const float4*)(p + DM);
            pr2 = *(const float4*)(p + 2*DM); pr3 = *(const float4*)(p + 3*DM);
        }
        bf16x8 af[4], bfr[4];
        #pragma unroll
        for (int i = 0; i < 4; ++i) af[i]  = *ap[i];
        #pragma unroll
        for (int j = 0; j < 4; ++j) bfr[j] = *bp[j];
        #pragma unroll
        for (int i = 0; i < 4; ++i)
            #pragma unroll
            for (int j = 0; j < 4; ++j)
                acc[i][j] = __builtin_amdgcn_mfma_f32_16x16x32_bf16(af[i], bfr[j], acc[i][j], 0, 0, 0);
    }

    #pragma unroll
    for (int j = 0; j < 4; ++j) {
        int ncol = ct*128 + wc*64 + j*16 + lr;
        float bb = (slab == 0) ? b2[e*DM + ncol] : 0.f;
        #pragma unroll
        for (int i = 0; i < 4; ++i) {
            #pragma unroll
            for (int r = 0; r < 4; ++r) {
                int trow = wr*64 + i*16 + lg*4 + r;
                if (r0 + trow < ne) {
                    int   brow = rid[trow];
                    float g    = rg[trow];
                    atomicAdd(&out[(size_t)brow*DM + ncol], g*(acc[i][j][r] + bb));
                }
            }
        }
    }
}

extern "C" void kernel_launch(void* const* d_in, const int* in_sizes, int n_in,
                              void* d_out, int out_size, void* d_ws, size_t ws_size,
                              hipStream_t stream) {
    const float* x  = (const float*)d_in[0];
    const float* Wg = (const float*)d_in[1];
    const float* bg = (const float*)d_in[2];
    const float* w1 = (const float*)d_in[3];
    const float* b1 = (const float*)d_in[4];
    const float* w2 = (const float*)d_in[5];
    const float* b2 = (const float*)d_in[6];
    float* out = (float*)d_out;

    // adaptive H-slab width by available scratch
    size_t need2048 = (size_t)WS_HBUF + (size_t)HPAD*2048*2;
    size_t need1024 = (size_t)WS_HBUF + (size_t)HPAD*1024*2;
    if (ws_size < need1024) return;
    int slabh = (ws_size >= need2048) ? 2048 : 1024;
    int nslab = HF / slabh;
    int ctn   = slabh / 128;

    char* ws = (char*)d_ws;
    int*   cnt   = (int*)  (ws + 0);
    float* imp   = (float*)(ws + 32);
    float* loadv = (float*)(ws + 64);
    int*   offs  = (int*)  (ws + 96);
    int*   rowsl = (int*)  (ws + WS_ROWS);
    float* rgate = (float*)(ws + WS_RGATE);
    unsigned short* xb   = (unsigned short*)(ws + WS_XB);
    unsigned short* hbuf = (unsigned short*)(ws + WS_HBUF);

    hipMemsetAsync(d_out, 0, (size_t)out_size * sizeof(float), stream);
    hipMemsetAsync(d_ws, 0, 256, stream);

    cvt_x<<<BATCH*DM/1024, 256, 0, stream>>>(x, xb);
    gate_kernel<<<BATCH/4, 256, 0, stream>>>(x, Wg, bg, out, cnt, imp, loadv, rowsl, rgate);
    finalize_kernel<<<1, 64, 0, stream>>>(cnt, imp, loadv, offs, out);

    for (int s = 0; s < nslab; ++s) {
        gemm1_mfma<<<NE*16*ctn, 256, 0, stream>>>(xb, w1, b1, cnt, offs, rowsl, hbuf, s, slabh);
        gemm2_mfma<<<NE*16*8,   256, 0, stream>>>(hbuf, w2, b2, cnt, offs, rowsl, rgate, out, s, slabh);
    }
}

// Round 5
// 957.000 us; speedup vs baseline: 2.8867x; 1.2742x over previous
//
#include <hip/hip_runtime.h>
#include <hip/hip_bf16.h>
#include <math.h>

#define BATCH 2048
#define DM    1024
#define HF    4096
#define NE    8

// d_out layout (floats)
#define OFF_GATES (BATCH*DM)
#define OFF_TOPI  (OFF_GATES + BATCH*NE)
#define OFF_LOSS  (OFF_TOPI + BATCH*2)
#define OFF_UTIL  (OFF_LOSS + 1)

// d_ws layout (bytes)
#define WS_ROWS   256
#define WS_RGATE  (WS_ROWS  + NE*BATCH*4)
#define WS_LOGIT  (WS_RGATE + NE*BATCH*4)
#define WS_XB     (WS_LOGIT + BATCH*NE*4)
#define WS_HBUF   (WS_XB + BATCH*DM*2)
#define HPAD      4224

typedef __attribute__((ext_vector_type(8))) short bf16x8;
typedef __attribute__((ext_vector_type(4))) float f32x4;

__device__ __forceinline__ unsigned short f2bf(float f) {
    __hip_bfloat16 h = __float2bfloat16(f);
    return *reinterpret_cast<unsigned short*>(&h);
}
__device__ __forceinline__ float f4get(const float4& v, int j) {
    return j == 0 ? v.x : j == 1 ? v.y : j == 2 ? v.z : v.w;
}
__device__ __forceinline__ float gelu_f(float v) {
    return 0.5f * v * (1.f + erff(v * 0.70710678118654752440f));
}

// ---------------- x -> bf16 copy ----------------
__global__ __launch_bounds__(256) void cvt_x(const float* __restrict__ x, unsigned short* __restrict__ xb) {
    int i = blockIdx.x * 256 + threadIdx.x;
    float4 v = reinterpret_cast<const float4*>(x)[i];
    uint2 o;
    o.x = (unsigned)f2bf(v.x) | ((unsigned)f2bf(v.y) << 16);
    o.y = (unsigned)f2bf(v.z) | ((unsigned)f2bf(v.w) << 16);
    reinterpret_cast<uint2*>(xb)[i] = o;
}

// ---------------- logits: one wave per row, no atomics ----------------
__global__ __launch_bounds__(256) void logits_kernel(
    const float* __restrict__ x, const float* __restrict__ Wg,
    const float* __restrict__ bg, float* __restrict__ logit)
{
    int lane = threadIdx.x & 63;
    int row  = blockIdx.x * 4 + (threadIdx.x >> 6);

    float a[NE] = {0.f,0.f,0.f,0.f,0.f,0.f,0.f,0.f};
    const float* xr = x + (size_t)row * DM;
    #pragma unroll
    for (int j = 0; j < DM/64; ++j) {
        int d = j*64 + lane;
        float xv = xr[d];
        const float4* wp = reinterpret_cast<const float4*>(Wg + (size_t)d*NE);
        float4 w0 = wp[0], w1v = wp[1];
        a[0] += xv*w0.x;  a[1] += xv*w0.y;  a[2] += xv*w0.z;  a[3] += xv*w0.w;
        a[4] += xv*w1v.x; a[5] += xv*w1v.y; a[6] += xv*w1v.z; a[7] += xv*w1v.w;
    }
    #pragma unroll
    for (int e = 0; e < NE; ++e) {
        #pragma unroll
        for (int off = 32; off > 0; off >>= 1) a[e] += __shfl_xor(a[e], off);
    }
    if (lane == 0) {
        float4 o0 = make_float4(a[0]+bg[0], a[1]+bg[1], a[2]+bg[2], a[3]+bg[3]);
        float4 o1 = make_float4(a[4]+bg[4], a[5]+bg[5], a[6]+bg[6], a[7]+bg[7]);
        float4* lp = reinterpret_cast<float4*>(logit + (size_t)row*NE);
        lp[0] = o0; lp[1] = o1;
    }
}

// ---------------- bookkeep: 8 blocks, one thread per row ----------------
// LDS aggregation -> 8 global atomics per array per block (vs 24K serialized).
__global__ __launch_bounds__(256) void bookkeep_kernel(
    const float* __restrict__ logit, float* __restrict__ out,
    int* __restrict__ cnt, float* __restrict__ imp, float* __restrict__ loadv,
    int* __restrict__ rowsl, float* __restrict__ rgate)
{
    __shared__ float s_im[NE], s_ld[NE];
    __shared__ int   s_slot[NE], s_base[NE];
    int t = threadIdx.x;
    if (t < NE) { s_im[t] = 0.f; s_ld[t] = 0.f; s_slot[t] = 0; }
    __syncthreads();

    int row = blockIdx.x * 256 + t;
    float lg[NE];
    {
        const float4* lp = reinterpret_cast<const float4*>(logit + (size_t)row*NE);
        float4 l0 = lp[0], l1 = lp[1];
        lg[0]=l0.x; lg[1]=l0.y; lg[2]=l0.z; lg[3]=l0.w;
        lg[4]=l1.x; lg[5]=l1.y; lg[6]=l1.z; lg[7]=l1.w;
    }
    float m = lg[0];
    #pragma unroll
    for (int e = 1; e < NE; ++e) m = fmaxf(m, lg[e]);
    float ex[NE], s = 0.f;
    #pragma unroll
    for (int e = 0; e < NE; ++e) { ex[e] = expf(lg[e] - m); s += ex[e]; }
    float inv = 1.f / s;
    #pragma unroll
    for (int e = 0; e < NE; ++e) atomicAdd(&s_ld[e], ex[e] * inv);

    int i1 = 0;
    #pragma unroll
    for (int e = 1; e < NE; ++e) if (lg[e] > lg[i1]) i1 = e;
    int i2 = (i1 == 0) ? 1 : 0;
    #pragma unroll
    for (int e = 0; e < NE; ++e) if (e != i1 && lg[e] > lg[i2]) i2 = e;
    float e2 = expf(lg[i2] - lg[i1]);
    float g1 = 1.f / (1.f + e2);
    float g2 = e2  / (1.f + e2);

    // gates + topi
    {
        float gv[NE];
        #pragma unroll
        for (int e = 0; e < NE; ++e) gv[e] = (e==i1) ? g1 : ((e==i2) ? g2 : 0.f);
        float4* gp = reinterpret_cast<float4*>(out + OFF_GATES + (size_t)row*NE);
        gp[0] = make_float4(gv[0],gv[1],gv[2],gv[3]);
        gp[1] = make_float4(gv[4],gv[5],gv[6],gv[7]);
        out[OFF_TOPI + row*2 + 0] = (float)i1;
        out[OFF_TOPI + row*2 + 1] = (float)i2;
    }

    atomicAdd(&s_im[i1], g1);
    atomicAdd(&s_im[i2], g2);
    int sl1 = atomicAdd(&s_slot[i1], 1);
    int sl2 = atomicAdd(&s_slot[i2], 1);
    __syncthreads();
    if (t < NE) {
        s_base[t] = atomicAdd(&cnt[t], s_slot[t]);
        atomicAdd(&imp[t],   s_im[t]);
        atomicAdd(&loadv[t], s_ld[t]);
    }
    __syncthreads();
    int p1 = s_base[i1] + sl1;
    rowsl[i1*BATCH + p1] = row;  rgate[i1*BATCH + p1] = g1;
    int p2 = s_base[i2] + sl2;
    rowsl[i2*BATCH + p2] = row;  rgate[i2*BATCH + p2] = g2;
}

// ---------------- finalize ----------------
__global__ void finalize_kernel(const int* __restrict__ cnt, const float* __restrict__ imp,
                                const float* __restrict__ loadv, int* __restrict__ offs,
                                float* __restrict__ out)
{
    if (threadIdx.x == 0) {
        float mi = 0.f, ml = 0.f;
        for (int e = 0; e < NE; ++e) { mi += imp[e]; ml += loadv[e]; }
        mi *= (1.f/NE); ml *= (1.f/NE);
        float vi = 0.f, vl = 0.f;
        for (int e = 0; e < NE; ++e) {
            float di = imp[e]  - mi; vi += di*di;
            float dl = loadv[e]- ml; vl += dl*dl;
        }
        vi *= (1.f/(NE-1)); vl *= (1.f/(NE-1));
        out[OFF_LOSS] = sqrtf(vi)/(mi + 1e-6f) + sqrtf(vl)/(ml + 1e-6f);
        int o = 0;
        for (int e = 0; e < NE; ++e) { offs[e] = o; o += cnt[e]; }
        offs[NE] = o;
    }
    if (threadIdx.x < NE)
        out[OFF_UTIL + threadIdx.x] = (float)cnt[threadIdx.x] * (1.f/BATCH);
}

// ===================== MFMA GEMM1: h = gelu(x_bf16 @ w1 + b1) =====================
// BM=BN=128, BK=32, 4 waves 2x2, 4x4 frags of 16x16x32. Works for any slabh (128-mult).
__global__ __launch_bounds__(256) void gemm1_mfma(
    const unsigned short* __restrict__ xb, const float* __restrict__ w1,
    const float* __restrict__ b1, const int* __restrict__ cnt,
    const int* __restrict__ offs, const int* __restrict__ rowsl,
    unsigned short* __restrict__ hbuf, int slab, int slabh)
{
    int ctn = slabh >> 7;
    int bid = blockIdx.x;
    int rt = bid & 15;               // innermost: blocks sharing B-panel adjacent
    int ct = (bid >> 4) % ctn;
    int e  = bid / (16*ctn);
    int ne = cnt[e];
    int r0 = rt * 128;
    if (r0 >= ne) return;
    int base = offs[e];

    __shared__ __align__(16) unsigned short As[128*32];
    __shared__ __align__(16) unsigned short Bs[128*32];
    __shared__ int rid[128];

    int t = threadIdx.x;
    if (t < 128) { int gi = r0 + t; rid[t] = rowsl[e*BATCH + (gi < ne ? gi : ne-1)]; }
    __syncthreads();

    int ar0 = t >> 2,        as0 = t & 3;
    int ar1 = 64 + (t >> 2), as1 = as0;
    const unsigned short* ag0 = xb + (size_t)rid[ar0]*DM + as0*8;
    const unsigned short* ag1 = xb + (size_t)rid[ar1]*DM + as1*8;
    int aw0 = ar0*32 + ((as0 ^ ((ar0 >> 2) & 3)) << 3);
    int aw1 = ar1*32 + ((as1 ^ ((ar1 >> 2) & 3)) << 3);

    int nq = t & 31, kq = t >> 5;
    const float* bgB = w1 + (size_t)e*DM*HF + (size_t)(4*kq)*HF + slab*slabh + ct*128 + 4*nq;
    int bw[4];
    #pragma unroll
    for (int jj = 0; jj < 4; ++jj) {
        int n = 4*nq + jj;
        bw[jj] = n*32 + (((kq >> 1) ^ ((n >> 2) & 3)) << 3) + ((kq & 1) << 2);
    }

    int lane = t & 63, wid = t >> 6, wr = wid >> 1, wc = wid & 1;
    int lr = lane & 15, lg = lane >> 4;
    const bf16x8* ap[4]; const bf16x8* bp[4];
    #pragma unroll
    for (int i = 0; i < 4; ++i) {
        int row = wr*64 + i*16 + lr;
        ap[i] = (const bf16x8*)&As[row*32 + ((lg ^ ((row >> 2) & 3)) << 3)];
    }
    #pragma unroll
    for (int j = 0; j < 4; ++j) {
        int n = wc*64 + j*16 + lr;
        bp[j] = (const bf16x8*)&Bs[n*32 + ((lg ^ ((n >> 2) & 3)) << 3)];
    }

    f32x4 acc[4][4];
    #pragma unroll
    for (int i = 0; i < 4; ++i)
        #pragma unroll
        for (int j = 0; j < 4; ++j) acc[i][j] = (f32x4){0.f,0.f,0.f,0.f};

    uint4 pa0, pa1; float4 pr0, pr1, pr2, pr3;
    pa0 = *(const uint4*)(ag0);
    pa1 = *(const uint4*)(ag1);
    { const float* p = bgB;
      pr0 = *(const float4*)(p); pr1 = *(const float4*)(p + HF);
      pr2 = *(const float4*)(p + 2*HF); pr3 = *(const float4*)(p + 3*HF); }

    for (int ks = 0; ks < DM/32; ++ks) {
        __syncthreads();
        *(uint4*)&As[aw0] = pa0;
        *(uint4*)&As[aw1] = pa1;
        #pragma unroll
        for (int jj = 0; jj < 4; ++jj) {
            uint2 o;
            o.x = (unsigned)f2bf(f4get(pr0,jj)) | ((unsigned)f2bf(f4get(pr1,jj)) << 16);
            o.y = (unsigned)f2bf(f4get(pr2,jj)) | ((unsigned)f2bf(f4get(pr3,jj)) << 16);
            *(uint2*)&Bs[bw[jj]] = o;
        }
        __syncthreads();
        if (ks + 1 < DM/32) {
            int k1 = (ks + 1) * 32;
            pa0 = *(const uint4*)(ag0 + k1);
            pa1 = *(const uint4*)(ag1 + k1);
            const float* p = bgB + (size_t)k1 * HF;
            pr0 = *(const float4*)(p); pr1 = *(const float4*)(p + HF);
            pr2 = *(const float4*)(p + 2*HF); pr3 = *(const float4*)(p + 3*HF);
        }
        bf16x8 af[4], bfr[4];
        #pragma unroll
        for (int i = 0; i < 4; ++i) af[i]  = *ap[i];
        #pragma unroll
        for (int j = 0; j < 4; ++j) bfr[j] = *bp[j];
        #pragma unroll
        for (int i = 0; i < 4; ++i)
            #pragma unroll
            for (int j = 0; j < 4; ++j)
                acc[i][j] = __builtin_amdgcn_mfma_f32_16x16x32_bf16(af[i], bfr[j], acc[i][j], 0, 0, 0);
    }

    const float* b1e = b1 + e*HF + slab*slabh + ct*128;
    #pragma unroll
    for (int j = 0; j < 4; ++j) {
        int ncol = wc*64 + j*16 + lr;
        float bb = b1e[ncol];
        #pragma unroll
        for (int i = 0; i < 4; ++i) {
            #pragma unroll
            for (int r = 0; r < 4; ++r) {
                int trow = wr*64 + i*16 + lg*4 + r;
                if (r0 + trow < ne) {
                    float v = gelu_f(acc[i][j][r] + bb);
                    hbuf[(size_t)(base + r0 + trow)*slabh + ct*128 + ncol] = f2bf(v);
                }
            }
        }
    }
}

// ===================== MFMA GEMM2: out += gate * (h @ w2 + b2) =====================
// K-sliced: grid = 1024 * nks; kslice = bid>>10. Accumulates via atomicAdd.
__global__ __launch_bounds__(256) void gemm2_mfma(
    const unsigned short* __restrict__ hbuf, const float* __restrict__ w2,
    const float* __restrict__ b2, const int* __restrict__ cnt,
    const int* __restrict__ offs, const int* __restrict__ rowsl,
    const float* __restrict__ rgate, float* __restrict__ out,
    int hstride, int klen, int kbase, int bias0)
{
    int bid = blockIdx.x;
    int ksl = bid >> 10;             // NE*16*8 = 1024 tiles per slice
    bid &= 1023;
    int rt = bid & 15;
    int ct = (bid >> 4) & 7;
    int e  = bid >> 7;
    int ne = cnt[e];
    int r0 = rt * 128;
    if (r0 >= ne) return;
    int base = offs[e];
    int hoff = ksl * klen;

    __shared__ __align__(16) unsigned short As[128*32];
    __shared__ __align__(16) unsigned short Bs[128*32];
    __shared__ int   rid[128];
    __shared__ float rg[128];

    int t = threadIdx.x;
    if (t < 128) {
        int gi = r0 + t; int ci = (gi < ne ? gi : ne-1);
        rid[t] = rowsl[e*BATCH + ci];
        rg[t]  = rgate[e*BATCH + ci];
    }
    __syncthreads();

    int ar0 = t >> 2,        as0 = t & 3;
    int ar1 = 64 + (t >> 2), as1 = as0;
    const unsigned short* ag0 = hbuf + (size_t)(base + r0 + ar0)*hstride + hoff + as0*8;
    const unsigned short* ag1 = hbuf + (size_t)(base + r0 + ar1)*hstride + hoff + as1*8;
    int aw0 = ar0*32 + ((as0 ^ ((ar0 >> 2) & 3)) << 3);
    int aw1 = ar1*32 + ((as1 ^ ((ar1 >> 2) & 3)) << 3);

    int nq = t & 31, kq = t >> 5;
    const float* bgB = w2 + (size_t)e*HF*DM + (size_t)(kbase + hoff + 4*kq)*DM + ct*128 + 4*nq;
    int bw[4];
    #pragma unroll
    for (int jj = 0; jj < 4; ++jj) {
        int n = 4*nq + jj;
        bw[jj] = n*32 + (((kq >> 1) ^ ((n >> 2) & 3)) << 3) + ((kq & 1) << 2);
    }

    int lane = t & 63, wid = t >> 6, wr = wid >> 1, wc = wid & 1;
    int lr = lane & 15, lg = lane >> 4;
    const bf16x8* ap[4]; const bf16x8* bp[4];
    #pragma unroll
    for (int i = 0; i < 4; ++i) {
        int row = wr*64 + i*16 + lr;
        ap[i] = (const bf16x8*)&As[row*32 + ((lg ^ ((row >> 2) & 3)) << 3)];
    }
    #pragma unroll
    for (int j = 0; j < 4; ++j) {
        int n = wc*64 + j*16 + lr;
        bp[j] = (const bf16x8*)&Bs[n*32 + ((lg ^ ((n >> 2) & 3)) << 3)];
    }

    f32x4 acc[4][4];
    #pragma unroll
    for (int i = 0; i < 4; ++i)
        #pragma unroll
        for (int j = 0; j < 4; ++j) acc[i][j] = (f32x4){0.f,0.f,0.f,0.f};

    int steps = klen >> 5;
    uint4 pa0, pa1; float4 pr0, pr1, pr2, pr3;
    pa0 = *(const uint4*)(ag0);
    pa1 = *(const uint4*)(ag1);
    { const float* p = bgB;
      pr0 = *(const float4*)(p); pr1 = *(const float4*)(p + DM);
      pr2 = *(const float4*)(p + 2*DM); pr3 = *(const float4*)(p + 3*DM); }

    for (int ks = 0; ks < steps; ++ks) {
        __syncthreads();
        *(uint4*)&As[aw0] = pa0;
        *(uint4*)&As[aw1] = pa1;
        #pragma unroll
        for (int jj = 0; jj < 4; ++jj) {
            uint2 o;
            o.x = (unsigned)f2bf(f4get(pr0,jj)) | ((unsigned)f2bf(f4get(pr1,jj)) << 16);
            o.y = (unsigned)f2bf(f4get(pr2,jj)) | ((unsigned)f2bf(f4get(pr3,jj)) << 16);
            *(uint2*)&Bs[bw[jj]] = o;
        }
        __syncthreads();
        if (ks + 1 < steps) {
            int k1 = (ks + 1) * 32;
            pa0 = *(const uint4*)(ag0 + k1);
            pa1 = *(const uint4*)(ag1 + k1);
            const float* p = bgB + (size_t)k1 * DM;
            pr0 = *(const float4*)(p); pr1 = *(const float4*)(p + DM);
            pr2 = *(const float4*)(p + 2*DM); pr3 = *(const float4*)(p + 3*DM);
        }
        bf16x8 af[4], bfr[4];
        #pragma unroll
        for (int i = 0; i < 4; ++i) af[i]  = *ap[i];
        #pragma unroll
        for (int j = 0; j < 4; ++j) bfr[j] = *bp[j];
        #pragma unroll
        for (int i = 0; i < 4; ++i)
            #pragma unroll
            for (int j = 0; j < 4; ++j)
                acc[i][j] = __builtin_amdgcn_mfma_f32_16x16x32_bf16(af[i], bfr[j], acc[i][j], 0, 0, 0);
    }

    int addb = (bias0 && ksl == 0);
    #pragma unroll
    for (int j = 0; j < 4; ++j) {
        int ncol = ct*128 + wc*64 + j*16 + lr;
        float bb = addb ? b2[e*DM + ncol] : 0.f;
        #pragma unroll
        for (int i = 0; i < 4; ++i) {
            #pragma unroll
            for (int r = 0; r < 4; ++r) {
                int trow = wr*64 + i*16 + lg*4 + r;
                if (r0 + trow < ne) {
                    int   brow = rid[trow];
                    float g    = rg[trow];
                    atomicAdd(&out[(size_t)brow*DM + ncol], g*(acc[i][j][r] + bb));
                }
            }
        }
    }
}

extern "C" void kernel_launch(void* const* d_in, const int* in_sizes, int n_in,
                              void* d_out, int out_size, void* d_ws, size_t ws_size,
                              hipStream_t stream) {
    const float* x  = (const float*)d_in[0];
    const float* Wg = (const float*)d_in[1];
    const float* bg = (const float*)d_in[2];
    const float* w1 = (const float*)d_in[3];
    const float* b1 = (const float*)d_in[4];
    const float* w2 = (const float*)d_in[5];
    const float* b2 = (const float*)d_in[6];
    float* out = (float*)d_out;

    size_t need_full = (size_t)WS_HBUF + (size_t)HPAD*4096*2;
    size_t need_2048 = (size_t)WS_HBUF + (size_t)HPAD*2048*2;
    size_t need_1024 = (size_t)WS_HBUF + (size_t)HPAD*1024*2;
    if (ws_size < need_1024) return;

    char* ws = (char*)d_ws;
    int*   cnt   = (int*)  (ws + 0);
    float* imp   = (float*)(ws + 32);
    float* loadv = (float*)(ws + 64);
    int*   offs  = (int*)  (ws + 96);
    int*   rowsl = (int*)  (ws + WS_ROWS);
    float* rgate = (float*)(ws + WS_RGATE);
    float* logit = (float*)(ws + WS_LOGIT);
    unsigned short* xb   = (unsigned short*)(ws + WS_XB);
    unsigned short* hbuf = (unsigned short*)(ws + WS_HBUF);

    hipMemsetAsync(d_out, 0, (size_t)out_size * sizeof(float), stream);
    hipMemsetAsync(d_ws, 0, 256, stream);

    cvt_x<<<BATCH*DM/1024, 256, 0, stream>>>(x, xb);
    logits_kernel<<<BATCH/4, 256, 0, stream>>>(x, Wg, bg, logit);
    bookkeep_kernel<<<BATCH/256, 256, 0, stream>>>(logit, out, cnt, imp, loadv, rowsl, rgate);
    finalize_kernel<<<1, 64, 0, stream>>>(cnt, imp, loadv, offs, out);

    if (ws_size >= need_full) {
        // one full-H gemm1 (~1024 active blocks), one K-split-4 gemm2 (~1024 active)
        gemm1_mfma<<<NE*16*32, 256, 0, stream>>>(xb, w1, b1, cnt, offs, rowsl, hbuf, 0, 4096);
        gemm2_mfma<<<NE*16*8*4, 256, 0, stream>>>(hbuf, w2, b2, cnt, offs, rowsl, rgate, out,
                                                  4096, 1024, 0, 1);
    } else {
        int slabh = (ws_size >= need_2048) ? 2048 : 1024;
        int nslab = HF / slabh;
        int ctn   = slabh / 128;
        for (int s = 0; s < nslab; ++s) {
            gemm1_mfma<<<NE*16*ctn, 256, 0, stream>>>(xb, w1, b1, cnt, offs, rowsl, hbuf, s, slabh);
            gemm2_mfma<<<NE*16*8*2, 256, 0, stream>>>(hbuf, w2, b2, cnt, offs, rowsl, rgate, out,
                                                      slabh, slabh/2, s*slabh, (s==0) ? 1 : 0);
        }
    }
}